// Round 13
// baseline (764.737 us; speedup 1.0000x reference)
//
#include <hip/hip_runtime.h>

#define NN 50000
#define NE 400000
#define NB 128
#define NINF (-__builtin_inff())

__device__ __forceinline__ float dpp_add16(float x) {
    int v = __float_as_int(x);
    x += __int_as_float(__builtin_amdgcn_update_dpp(0, v, 0xB1, 0xF, 0xF, true));  // quad_perm(1,0,3,2)
    v = __float_as_int(x);
    x += __int_as_float(__builtin_amdgcn_update_dpp(0, v, 0x4E, 0xF, 0xF, true));  // quad_perm(2,3,0,1)
    v = __float_as_int(x);
    x += __int_as_float(__builtin_amdgcn_update_dpp(0, v, 0x141, 0xF, 0xF, true)); // row_half_mirror
    v = __float_as_int(x);
    x += __int_as_float(__builtin_amdgcn_update_dpp(0, v, 0x140, 0xF, 0xF, true)); // row_mirror
    return x;
}

// ============================ CSR build ============================
__global__ __launch_bounds__(256) void k_hist(const int* __restrict__ dstv, int* __restrict__ deg) {
    int e = blockIdx.x * 256 + threadIdx.x;
    if (e < NE) atomicAdd(&deg[dstv[e]], 1);
}

__global__ __launch_bounds__(256) void k_scan1(const int* __restrict__ deg, int* __restrict__ bsum,
                                               int* __restrict__ cnt) {
    __shared__ int ws[4];
    const int tid = threadIdx.x, lane = tid & 63, w = tid >> 6;
    const int i = blockIdx.x * 256 + tid;
    if (i < NN) cnt[i] = 0;
    int v = (i < NN) ? deg[i] : 0;
    #pragma unroll
    for (int off = 32; off; off >>= 1) v += __shfl_xor(v, off);
    if (lane == 0) ws[w] = v;
    __syncthreads();
    if (tid == 0) bsum[blockIdx.x] = ws[0] + ws[1] + ws[2] + ws[3];
}

// also zeroes stats (3*768 floats) + 3 done-counters
__global__ __launch_bounds__(256) void k_scan2(const int* __restrict__ bsum, int* __restrict__ boff, int nblk,
                                               float* __restrict__ stats) {
    __shared__ int ws[4];
    const int tid = threadIdx.x, lane = tid & 63, w = tid >> 6;
    for (int i = tid; i < 2308; i += 256) stats[i] = 0.f;
    int v = (tid < nblk) ? bsum[tid] : 0;
    int incl = v;
    #pragma unroll
    for (int off = 1; off < 64; off <<= 1) {
        int t = __shfl_up(incl, off);
        if (lane >= off) incl += t;
    }
    if (lane == 63) ws[w] = incl;
    __syncthreads();
    int add = 0;
    for (int k = 0; k < w; ++k) add += ws[k];
    if (tid < nblk) boff[tid] = add + incl - v;
}

__global__ __launch_bounds__(256) void k_scan3(const int* __restrict__ deg, const int* __restrict__ boff,
                                               int* __restrict__ rowptr) {
    __shared__ int ws[4];
    const int tid = threadIdx.x, lane = tid & 63, w = tid >> 6;
    const int i = blockIdx.x * 256 + tid;
    int v = (i < NN) ? deg[i] : 0;
    int incl = v;
    #pragma unroll
    for (int off = 1; off < 64; off <<= 1) {
        int t = __shfl_up(incl, off);
        if (lane >= off) incl += t;
    }
    if (lane == 63) ws[w] = incl;
    __syncthreads();
    int add = boff[blockIdx.x];
    for (int k = 0; k < w; ++k) add += ws[k];
    if (i < NN) rowptr[i + 1] = add + incl;
    if (i == 0) rowptr[0] = 0;
}

__global__ __launch_bounds__(256) void k_scatter(const int* __restrict__ dstv, const int* __restrict__ srcv,
                                                 const float* __restrict__ eattr, const int* __restrict__ rowptr,
                                                 int* __restrict__ cnt, int* __restrict__ eid,
                                                 int* __restrict__ src_perm, float4* __restrict__ ea_perm,
                                                 int use_perm) {
    int e = blockIdx.x * 256 + threadIdx.x;
    if (e < NE) {
        int d = dstv[e];
        int pos = rowptr[d] + atomicAdd(&cnt[d], 1);
        eid[pos] = e;
        if (use_perm) {
            src_perm[pos] = srcv[e];
            ea_perm[(size_t)pos * 2] = ((const float4*)eattr)[e * 2];
            ea_perm[(size_t)pos * 2 + 1] = ((const float4*)eattr)[e * 2 + 1];
        }
    }
}

// ============================ GEMM: [N,64] @ [64,256] -> xl / xr ============================
// 256 rows x 128 cols per block; 16x8 microtile (acc=128 regs); K chunked x4 (~25KB LDS).
// Per k-step: 6 b128 LDS reads per 128 FLOP -> VALU-bound at 3 blocks/CU (LDS pipe 25% slack).
// __launch_bounds__(256,3): 170-VGPR budget. If VGPR counter shows spill (r10 symptom:
// WRITE_SIZE inflation), revert to 8x8 at (256,4).
__global__ __launch_bounds__(256, 3) void k_gemm64(const float* __restrict__ A, const float* __restrict__ Wl,
                                                   const float* __restrict__ Wr, float* __restrict__ Cl,
                                                   float* __restrict__ Cr, const float* __restrict__ stats) {
    __shared__ float At[16 * 260];  // 16,640 B
    __shared__ float Ws[16 * 128];  // 8,192 B
    const int tid = threadIdx.x;
    const int mat = blockIdx.y >> 1, ch = blockIdx.y & 1;
    const float* W = mat ? Wr : Wl;
    float* C = mat ? Cr : Cl;
    const int r0b = blockIdx.x * 256;
    const int cg = tid & 15; // cols ch*128 + cg*8 ..+7
    const int rg = tid >> 4; // rows rg*16..+15

    float acc[16][8];
    if (stats) {
        const float* shW = stats + 256 + mat * 256 + ch * 128 + cg * 8;
        const float4 i0 = *(const float4*)shW;
        const float4 i1 = *(const float4*)(shW + 4);
        #pragma unroll
        for (int rr = 0; rr < 16; ++rr) {
            acc[rr][0] = i0.x; acc[rr][1] = i0.y; acc[rr][2] = i0.z; acc[rr][3] = i0.w;
            acc[rr][4] = i1.x; acc[rr][5] = i1.y; acc[rr][6] = i1.z; acc[rr][7] = i1.w;
        }
    } else {
        #pragma unroll
        for (int rr = 0; rr < 16; ++rr)
            #pragma unroll
            for (int j = 0; j < 8; ++j) acc[rr][j] = 0.f;
    }

    for (int kc = 0; kc < 4; ++kc) {
        if (kc) __syncthreads();
        // W chunk: k = kc*16 + (0..15), this 128-col half (scaled by sc if BN)
        for (int i = tid; i < 512; i += 256) {
            const int k = i >> 5, c4 = i & 31;
            float4 v = ((const float4*)W)[(kc * 16 + k) * 64 + ch * 32 + c4];
            if (stats) {
                const float s = stats[128 + kc * 16 + k];
                v.x *= s; v.y *= s; v.z *= s; v.w *= s;
            }
            ((float4*)Ws)[i] = v;
        }
        // A chunk transposed: At[k][r], k in [0,16); A rows are 64 floats = 16 float4s
        for (int i = tid; i < 1024; i += 256) {
            const int r = i >> 2, c4 = i & 3;
            const int rgl = (r0b + r < NN) ? (r0b + r) : (NN - 1);
            const float4 v = ((const float4*)A)[rgl * 16 + kc * 4 + c4];
            At[(c4 * 4 + 0) * 260 + r] = v.x;
            At[(c4 * 4 + 1) * 260 + r] = v.y;
            At[(c4 * 4 + 2) * 260 + r] = v.z;
            At[(c4 * 4 + 3) * 260 + r] = v.w;
        }
        __syncthreads();
        #pragma unroll 2
        for (int k = 0; k < 16; ++k) {
            const float4 a0 = *(const float4*)(At + k * 260 + rg * 16);
            const float4 a1 = *(const float4*)(At + k * 260 + rg * 16 + 4);
            const float4 a2 = *(const float4*)(At + k * 260 + rg * 16 + 8);
            const float4 a3 = *(const float4*)(At + k * 260 + rg * 16 + 12);
            const float4 w0 = *(const float4*)(Ws + k * 128 + cg * 8);
            const float4 w1 = *(const float4*)(Ws + k * 128 + cg * 8 + 4);
            const float ar[16] = {a0.x, a0.y, a0.z, a0.w, a1.x, a1.y, a1.z, a1.w,
                                  a2.x, a2.y, a2.z, a2.w, a3.x, a3.y, a3.z, a3.w};
            #pragma unroll
            for (int rr = 0; rr < 16; ++rr) {
                acc[rr][0] = fmaf(ar[rr], w0.x, acc[rr][0]);
                acc[rr][1] = fmaf(ar[rr], w0.y, acc[rr][1]);
                acc[rr][2] = fmaf(ar[rr], w0.z, acc[rr][2]);
                acc[rr][3] = fmaf(ar[rr], w0.w, acc[rr][3]);
                acc[rr][4] = fmaf(ar[rr], w1.x, acc[rr][4]);
                acc[rr][5] = fmaf(ar[rr], w1.y, acc[rr][5]);
                acc[rr][6] = fmaf(ar[rr], w1.z, acc[rr][6]);
                acc[rr][7] = fmaf(ar[rr], w1.w, acc[rr][7]);
            }
        }
    }
    #pragma unroll
    for (int rr = 0; rr < 16; ++rr) {
        const int r = r0b + rg * 16 + rr;
        if (r < NN) {
            float* cp = C + (size_t)r * 256 + ch * 128 + cg * 8;
            *(float4*)cp = make_float4(acc[rr][0], acc[rr][1], acc[rr][2], acc[rr][3]);
            *(float4*)(cp + 4) = make_float4(acc[rr][4], acc[rr][5], acc[rr][6], acc[rr][7]);
        }
    }
}

// ============================ Fused edge kernel (r7 3-slot; grid 4096 this round) ============================
template <bool PERM>
__global__ __launch_bounds__(256, 4) void k_agg(const float* __restrict__ xl, float* __restrict__ xragg,
                                                const float* __restrict__ att, const float* __restrict__ gatb,
                                                const int* __restrict__ rowptr, const int* __restrict__ eid,
                                                const int* __restrict__ srcv, const float* __restrict__ eattr,
                                                const int* __restrict__ src_perm, const float4* __restrict__ ea_perm,
                                                const float* __restrict__ We) {
    const int lane = threadIdx.x & 63;
    const float4 we0 = ((const float4*)(We + 0 * 256))[lane];
    const float4 we1 = ((const float4*)(We + 1 * 256))[lane];
    const float4 we2 = ((const float4*)(We + 2 * 256))[lane];
    const float4 we3 = ((const float4*)(We + 3 * 256))[lane];
    const float4 we4 = ((const float4*)(We + 4 * 256))[lane];
    const float4 we5 = ((const float4*)(We + 5 * 256))[lane];
    const float4 we6 = ((const float4*)(We + 6 * 256))[lane];
    const float4 we7 = ((const float4*)(We + 7 * 256))[lane];
    const float4 attf = ((const float4*)att)[lane];
    const float4 gbf = ((const float4*)gatb)[lane];
    const int nw = gridDim.x * (blockDim.x >> 6);
    const int wid = blockIdx.x * (blockDim.x >> 6) + (threadIdx.x >> 6);

#define LOADE(X, idx)                                                          \
    {                                                                          \
        int s_;                                                                \
        const float4* eap_;                                                    \
        if (PERM) {                                                            \
            s_ = src_perm[idx];                                                \
            eap_ = ea_perm + (size_t)(idx) * 2;                                \
        } else {                                                               \
            const int e_ = eid[idx];                                           \
            s_ = srcv[e_];                                                     \
            eap_ = (const float4*)(eattr + (size_t)e_ * 8);                    \
        }                                                                      \
        X##x = ((const float4*)(xl + (size_t)s_ * 256))[lane];                 \
        X##a = eap_[0];                                                        \
        X##b = eap_[1];                                                        \
    }

#define PROC(X)                                                                \
    {                                                                          \
        float v0 = fmaf(X##a.x, we0.x, xr.x), v1 = fmaf(X##a.x, we0.y, xr.y);  \
        float v2 = fmaf(X##a.x, we0.z, xr.z), v3 = fmaf(X##a.x, we0.w, xr.w);  \
        v0 = fmaf(X##a.y, we1.x, v0); v1 = fmaf(X##a.y, we1.y, v1);            \
        v2 = fmaf(X##a.y, we1.z, v2); v3 = fmaf(X##a.y, we1.w, v3);            \
        v0 = fmaf(X##a.z, we2.x, v0); v1 = fmaf(X##a.z, we2.y, v1);            \
        v2 = fmaf(X##a.z, we2.z, v2); v3 = fmaf(X##a.z, we2.w, v3);            \
        v0 = fmaf(X##a.w, we3.x, v0); v1 = fmaf(X##a.w, we3.y, v1);            \
        v2 = fmaf(X##a.w, we3.z, v2); v3 = fmaf(X##a.w, we3.w, v3);            \
        v0 = fmaf(X##b.x, we4.x, v0); v1 = fmaf(X##b.x, we4.y, v1);            \
        v2 = fmaf(X##b.x, we4.z, v2); v3 = fmaf(X##b.x, we4.w, v3);            \
        v0 = fmaf(X##b.y, we5.x, v0); v1 = fmaf(X##b.y, we5.y, v1);            \
        v2 = fmaf(X##b.y, we5.z, v2); v3 = fmaf(X##b.y, we5.w, v3);            \
        v0 = fmaf(X##b.z, we6.x, v0); v1 = fmaf(X##b.z, we6.y, v1);            \
        v2 = fmaf(X##b.z, we6.z, v2); v3 = fmaf(X##b.z, we6.w, v3);            \
        v0 = fmaf(X##b.w, we7.x, v0); v1 = fmaf(X##b.w, we7.y, v1);            \
        v2 = fmaf(X##b.w, we7.z, v2); v3 = fmaf(X##b.w, we7.w, v3);            \
        v0 += X##x.x; v1 += X##x.y; v2 += X##x.z; v3 += X##x.w;                \
        v0 = fmaxf(v0, 0.2f * v0); v1 = fmaxf(v1, 0.2f * v1);                  \
        v2 = fmaxf(v2, 0.2f * v2); v3 = fmaxf(v3, 0.2f * v3);                  \
        float part = v0 * attf.x;                                              \
        part = fmaf(v1, attf.y, part);                                         \
        part = fmaf(v2, attf.z, part);                                         \
        part = fmaf(v3, attf.w, part);                                         \
        part = dpp_add16(part);                                                \
        const float p = __expf(part);                                          \
        den += p;                                                              \
        c0 = fmaf(p, X##x.x, c0);                                              \
        c1 = fmaf(p, X##x.y, c1);                                              \
        c2 = fmaf(p, X##x.z, c2);                                              \
        c3 = fmaf(p, X##x.w, c3);                                              \
    }

    for (int n = wid; n < NN; n += nw) {
        const int e0 = rowptr[n], e1 = rowptr[n + 1];
        const float4 xr = ((const float4*)(xragg + (size_t)n * 256))[lane];
        float den = 0.f, c0 = 0.f, c1 = 0.f, c2 = 0.f, c3 = 0.f;
        float4 Ax, Aa, Ab, Bx, Ba, Bb, Cx, Ca, Cb;
        const int cnt = e1 - e0;
        if (cnt > 0) {
            LOADE(A, e0);
            if (cnt > 1) LOADE(B, e0 + 1);
            if (cnt > 2) LOADE(C, e0 + 2);
            int i = e0;
            for (; i + 5 < e1; i += 3) {
                PROC(A);
                LOADE(A, i + 3);
                PROC(B);
                LOADE(B, i + 4);
                PROC(C);
                LOADE(C, i + 5);
            }
            const int m = e1 - i; // 1..5
            PROC(A);
            if (m >= 2) PROC(B);
            if (m >= 3) PROC(C);
            if (m >= 4) { LOADE(A, i + 3); PROC(A); }
            if (m == 5) { LOADE(B, i + 4); PROC(B); }
        }
        float4 o;
        if (cnt > 0) {
            const float inv = 1.0f / den;
            o.x = fmaf(c0, inv, gbf.x);
            o.y = fmaf(c1, inv, gbf.y);
            o.z = fmaf(c2, inv, gbf.z);
            o.w = fmaf(c3, inv, gbf.w);
        } else {
            o = gbf;
        }
        ((float4*)(xragg + (size_t)n * 256))[lane] = o;
    }
#undef LOADE
#undef PROC
}

// ============================ tr GEMM + fused BN finalize ============================
// 256 rows x 64 cols per block, 8x8 microtile; K chunked x8 (~42KB LDS) -- r7 best config.
// Last block (done-counter) computes sc/sh/shW_l/shW_r into stats for the next layer's gemm64.
__global__ __launch_bounds__(256, 4) void k_tr(const float* __restrict__ A, const float* __restrict__ W,
                                               const float* __restrict__ bias, float* __restrict__ Hout,
                                               float* __restrict__ stats, const float* __restrict__ g,
                                               const float* __restrict__ b, const float* __restrict__ Wln,
                                               const float* __restrict__ Wrn, int* __restrict__ done,
                                               int do_fin) {
    __shared__ float At[32 * 260]; // 33,280 B
    __shared__ float Ws[32 * 64];  // 8,192 B
    __shared__ float red[128];
    __shared__ int isLast;
    const int tid = threadIdx.x;
    const int cg = tid & 7;  // cols cg*8..+7
    const int rg = tid >> 3; // rows rg*8..+7 (0..31)
    const int r0b = blockIdx.x * 256;

    float acc[8][8];
    #pragma unroll
    for (int rr = 0; rr < 8; ++rr)
        #pragma unroll
        for (int j = 0; j < 8; ++j)
            acc[rr][j] = bias[cg * 8 + j];

    for (int kc = 0; kc < 8; ++kc) {
        if (kc) __syncthreads();
        for (int i = tid; i < 512; i += 256)
            ((float4*)Ws)[i] = ((const float4*)(W + kc * 2048))[i];
        // A chunk transposed: A rows are 256 floats = 64 float4s; chunk covers 8 float4s
        for (int i = tid; i < 2048; i += 256) {
            const int r = i >> 3, c4 = i & 7;
            const int rgl = (r0b + r < NN) ? (r0b + r) : (NN - 1);
            const float4 v = ((const float4*)A)[(size_t)rgl * 64 + kc * 8 + c4];
            At[(c4 * 4 + 0) * 260 + r] = v.x;
            At[(c4 * 4 + 1) * 260 + r] = v.y;
            At[(c4 * 4 + 2) * 260 + r] = v.z;
            At[(c4 * 4 + 3) * 260 + r] = v.w;
        }
        __syncthreads();
        #pragma unroll 4
        for (int k = 0; k < 32; ++k) {
            const float4 a0 = *(const float4*)(At + k * 260 + rg * 8);
            const float4 a1 = *(const float4*)(At + k * 260 + rg * 8 + 4);
            const float4 w0 = *(const float4*)(Ws + k * 64 + cg * 8);
            const float4 w1 = *(const float4*)(Ws + k * 64 + cg * 8 + 4);
            const float ar[8] = {a0.x, a0.y, a0.z, a0.w, a1.x, a1.y, a1.z, a1.w};
            #pragma unroll
            for (int rr = 0; rr < 8; ++rr) {
                acc[rr][0] = fmaf(ar[rr], w0.x, acc[rr][0]);
                acc[rr][1] = fmaf(ar[rr], w0.y, acc[rr][1]);
                acc[rr][2] = fmaf(ar[rr], w0.z, acc[rr][2]);
                acc[rr][3] = fmaf(ar[rr], w0.w, acc[rr][3]);
                acc[rr][4] = fmaf(ar[rr], w1.x, acc[rr][4]);
                acc[rr][5] = fmaf(ar[rr], w1.y, acc[rr][5]);
                acc[rr][6] = fmaf(ar[rr], w1.z, acc[rr][6]);
                acc[rr][7] = fmaf(ar[rr], w1.w, acc[rr][7]);
            }
        }
    }
    float lsum[8], lsq[8];
    #pragma unroll
    for (int j = 0; j < 8; ++j) { lsum[j] = 0.f; lsq[j] = 0.f; }
    #pragma unroll
    for (int rr = 0; rr < 8; ++rr) {
        const int r = r0b + rg * 8 + rr;
        if (r < NN) {
            float v[8];
            #pragma unroll
            for (int j = 0; j < 8; ++j) {
                v[j] = fmaxf(acc[rr][j], 0.f);
                lsum[j] += v[j];
                lsq[j] = fmaf(v[j], v[j], lsq[j]);
            }
            float* hp = Hout + (size_t)r * 64;
            *(float4*)(hp + cg * 8) = make_float4(v[0], v[1], v[2], v[3]);
            *(float4*)(hp + cg * 8 + 4) = make_float4(v[4], v[5], v[6], v[7]);
        }
    }
    __syncthreads();
    if (tid < 128) red[tid] = 0.f;
    __syncthreads();
    #pragma unroll
    for (int j = 0; j < 8; ++j) {
        atomicAdd(&red[cg * 8 + j], lsum[j]);
        atomicAdd(&red[64 + cg * 8 + j], lsq[j]);
    }
    __syncthreads();
    if (tid < 64) {
        atomicAdd(&stats[tid], red[tid]);
        atomicAdd(&stats[64 + tid], red[64 + tid]);
    }
    if (!do_fin) return;
    // ---- last-block BN finalize (replaces k_bnfin launch) ----
    __threadfence();
    if (tid == 0) {
        const int t = atomicAdd(done, 1);
        isLast = (t == (int)gridDim.x - 1);
    }
    __syncthreads();
    if (!isLast) return;
    if (tid < 64) {
        const float sum = atomicAdd(&stats[tid], 0.f);
        const float sq  = atomicAdd(&stats[64 + tid], 0.f);
        const float mu = sum * (1.0f / (float)NN);
        const float var = sq * (1.0f / (float)NN) - mu * mu;
        const float rstd = rsqrtf(var + 1e-5f);
        const float sc = g[tid] * rstd;
        const float sh = fmaf(-mu, sc, b[tid]);
        stats[128 + tid] = sc;
        stats[192 + tid] = sh;
        red[tid] = sh;
    }
    __syncthreads();
    float al = 0.f, ar2 = 0.f;
    for (int k = 0; k < 64; ++k) {
        al = fmaf(red[k], Wln[k * 256 + tid], al);
        ar2 = fmaf(red[k], Wrn[k * 256 + tid], ar2);
    }
    stats[256 + tid] = al;
    stats[512 + tid] = ar2;
}

// ============================ fused gate + pool + BN fold + MLP head ============================
__global__ __launch_bounds__(256) void k_poolhead(const float* __restrict__ h, const float* __restrict__ gw,
                                                  const int* __restrict__ bidx, const float* __restrict__ stats,
                                                  const float* __restrict__ bg, const float* __restrict__ bb,
                                                  const float* __restrict__ fc, const float* __restrict__ nrot,
                                                  const float* __restrict__ W1, const float* __restrict__ b1,
                                                  const float* __restrict__ W2, const float* __restrict__ b2,
                                                  const float* __restrict__ W3, const float* __restrict__ b3,
                                                  const float* __restrict__ W4, const float* __restrict__ b4,
                                                  float* __restrict__ out) {
    __shared__ float gate_s[1024];
    __shared__ float red[4];
    __shared__ float pp[4][64];
    __shared__ float scb[64], shb[64];
    __shared__ float z[66], a1[256], a2[128], a3[64];
    const int b = blockIdx.x, tid = threadIdx.x, lane = tid & 63, w = tid >> 6;
    if (tid < 64) {
        const float mu = stats[tid] * (1.0f / (float)NN);
        const float var = stats[64 + tid] * (1.0f / (float)NN) - mu * mu;
        const float rstd = rsqrtf(var + 1e-5f);
        const float sc = bg[tid] * rstd;
        scb[tid] = sc;
        shb[tid] = fmaf(-mu, sc, bb[tid]);
    }
    int lo = 0, hi = NN;
    while (lo < hi) { int mid = (lo + hi) >> 1; if (bidx[mid] < b) lo = mid + 1; else hi = mid; }
    const int s0 = lo;
    lo = 0; hi = NN;
    while (lo < hi) { int mid = (lo + hi) >> 1; if (bidx[mid] < b + 1) lo = mid + 1; else hi = mid; }
    const int s1 = lo;
    const int seg = s1 - s0;
    __syncthreads();

    const float gwv = gw[lane] * scb[lane];
    for (int i = s0 + w; i < s1; i += 4) {
        float p = h[(size_t)i * 64 + lane] * gwv;
        #pragma unroll
        for (int off = 32; off; off >>= 1) p += __shfl_xor(p, off);
        if (lane == 0) gate_s[i - s0] = p;
    }
    __syncthreads();
    float v = NINF;
    for (int i = tid; i < seg; i += 256) v = fmaxf(v, gate_s[i]);
    #pragma unroll
    for (int off = 32; off; off >>= 1) v = fmaxf(v, __shfl_xor(v, off));
    if (lane == 0) red[w] = v;
    __syncthreads();
    const float mx = fmaxf(fmaxf(red[0], red[1]), fmaxf(red[2], red[3]));
    __syncthreads();
    float d = 0.f;
    for (int i = tid; i < seg; i += 256) {
        const float ex = __expf(gate_s[i] - mx);
        gate_s[i] = ex;
        d += ex;
    }
    #pragma unroll
    for (int off = 32; off; off >>= 1) d += __shfl_xor(d, off);
    if (lane == 0) red[w] = d;
    __syncthreads();
    const float den = red[0] + red[1] + red[2] + red[3];
    const int c = tid & 63, ro = tid >> 6;
    float acc = 0.f;
    for (int i = s0 + ro; i < s1; i += 4) acc = fmaf(gate_s[i - s0], h[(size_t)i * 64 + c], acc);
    pp[ro][c] = acc;
    __syncthreads();
    if (tid < 64) {
        const float raw = (pp[0][tid] + pp[1][tid] + pp[2][tid] + pp[3][tid]) / den;
        z[tid] = (seg > 0) ? fmaf(raw, scb[tid], shb[tid]) : shb[tid];
    }
    if (tid == 64) z[64] = fc[b];
    if (tid == 65) z[65] = nrot[b];
    __syncthreads();
    float s = b1[tid];
    for (int k = 0; k < 66; ++k) s = fmaf(z[k], W1[k * 256 + tid], s);
    a1[tid] = fmaxf(s, 0.f);
    __syncthreads();
    if (tid < 128) {
        float s2 = b2[tid];
        for (int k = 0; k < 256; ++k) s2 = fmaf(a1[k], W2[k * 128 + tid], s2);
        a2[tid] = fmaxf(s2, 0.f);
    }
    __syncthreads();
    if (tid < 64) {
        float s3 = b3[tid];
        for (int k = 0; k < 128; ++k) s3 = fmaf(a2[k], W3[k * 64 + tid], s3);
        a3[tid] = fmaxf(s3, 0.f);
    }
    __syncthreads();
    if (tid < 64) {
        float p = a3[tid] * W4[tid];
        #pragma unroll
        for (int off = 32; off; off >>= 1) p += __shfl_xor(p, off);
        if (tid == 0) out[b] = p + b4[0];
    }
}

// ============================ launch ============================
extern "C" void kernel_launch(void* const* d_in, const int* in_sizes, int n_in,
                              void* d_out, int out_size, void* d_ws, size_t ws_size,
                              hipStream_t stream) {
    const float* x     = (const float*)d_in[0];
    const int*   ei    = (const int*)d_in[1];
    const float* eattr = (const float*)d_in[2];
    const float* fcv   = (const float*)d_in[3];
    const float* nrot  = (const float*)d_in[4];
    const int*   bidx  = (const int*)d_in[5];
    const float* Wl    = (const float*)d_in[6];
    const float* Wr    = (const float*)d_in[7];
    const float* We    = (const float*)d_in[8];
    const float* att   = (const float*)d_in[9];
    const float* gatb  = (const float*)d_in[10];
    const float* trW   = (const float*)d_in[11];
    const float* trb   = (const float*)d_in[12];
    const float* bng   = (const float*)d_in[13];
    const float* bnb   = (const float*)d_in[14];
    const float* gateW = (const float*)d_in[15];
    const float* W1    = (const float*)d_in[17];
    const float* b1    = (const float*)d_in[18];
    const float* W2    = (const float*)d_in[19];
    const float* b2    = (const float*)d_in[20];
    const float* W3    = (const float*)d_in[21];
    const float* b3    = (const float*)d_in[22];
    const float* W4    = (const float*)d_in[23];
    const float* b4    = (const float*)d_in[24];
    float* out = (float*)d_out;

    const int* srcv = ei;
    const int* dstv = ei + NE;

    char* w = (char*)d_ws;
    float*  xl       = (float*)(w);                 // 51,200,000
    float*  xragg    = (float*)(w + 51200000);      // 51,200,000 (xr in, agg out)
    float*  hbuf     = (float*)(w + 102400000);     // 12,800,000
    int*    deg      = (int*)  (w + 102400000);     // overlaps hbuf (dead before first k_tr)
    int*    cnt      = (int*)  (w + 102600000);     // overlaps hbuf
    int*    eid      = (int*)  (w + 115200000);     // 1,600,000
    int*    rowptr   = (int*)  (w + 116800000);     // 200,004
    float*  stats    = (float*)(w + 117000064);     // 2304 floats (3*768) + 3 done-counters
    int*    done     = (int*)  (w + 117000064 + 2304 * 4);
    int*    bsum     = (int*)  (w + 117010176);     // 784
    int*    boff     = (int*)  (w + 117012224);     // 784
    int*    src_perm = (int*)  (w + 117042048);     // 1,600,000
    float4* ea_perm  = (float4*)(w + 118642048);    // 12,800,000 -> 131,442,048
    const bool use_perm = (ws_size >= (size_t)131442048);
    const int NBLK = (NN + 255) / 256; // 196

    hipMemsetAsync(deg, 0, 200000, stream);
    k_hist<<<(NE + 255) / 256, 256, 0, stream>>>(dstv, deg);
    k_scan1<<<NBLK, 256, 0, stream>>>(deg, bsum, cnt);
    k_scan2<<<1, 256, 0, stream>>>(bsum, boff, NBLK, stats);
    k_scan3<<<NBLK, 256, 0, stream>>>(deg, boff, rowptr);
    k_scatter<<<(NE + 255) / 256, 256, 0, stream>>>(dstv, srcv, eattr, rowptr, cnt, eid,
                                                    src_perm, ea_perm, use_perm ? 1 : 0);

    const float* hin = x;
    for (int l = 0; l < 3; ++l) {
        const float* st = (l == 0) ? nullptr : (stats + (l - 1) * 768);
        dim3 gg((NN + 255) / 256, 4);
        k_gemm64<<<gg, 256, 0, stream>>>(hin, Wl + l * 16384, Wr + l * 16384, xl, xragg, st);
        if (use_perm)
            k_agg<true><<<4096, 256, 0, stream>>>(xl, xragg, att + l * 256, gatb + l * 256, rowptr,
                                                  eid, srcv, eattr, src_perm, ea_perm, We + l * 2048);
        else
            k_agg<false><<<4096, 256, 0, stream>>>(xl, xragg, att + l * 256, gatb + l * 256, rowptr,
                                                   eid, srcv, eattr, src_perm, ea_perm, We + l * 2048);
        const float* Wln = (l < 2) ? (Wl + (l + 1) * 16384) : Wl;
        const float* Wrn = (l < 2) ? (Wr + (l + 1) * 16384) : Wr;
        k_tr<<<(NN + 255) / 256, 256, 0, stream>>>(xragg, trW + l * 16384, trb + l * 64, hbuf,
                                                   stats + l * 768, bng + l * 64, bnb + l * 64,
                                                   Wln, Wrn, done + l, (l < 2) ? 1 : 0);
        hin = hbuf;
    }
    k_poolhead<<<NB, 256, 0, stream>>>(hbuf, gateW, bidx, stats + 2 * 768, bng + 128, bnb + 128,
                                       fcv, nrot, W1, b1, W2, b2, W3, b3, W4, b4, out);
}

// Round 14
// 696.957 us; speedup vs baseline: 1.0973x; 1.0973x over previous
//
#include <hip/hip_runtime.h>

#define NN 50000
#define NE 400000
#define NB 128
#define NINF (-__builtin_inff())

__device__ __forceinline__ float dpp_add16(float x) {
    int v = __float_as_int(x);
    x += __int_as_float(__builtin_amdgcn_update_dpp(0, v, 0xB1, 0xF, 0xF, true));  // quad_perm(1,0,3,2)
    v = __float_as_int(x);
    x += __int_as_float(__builtin_amdgcn_update_dpp(0, v, 0x4E, 0xF, 0xF, true));  // quad_perm(2,3,0,1)
    v = __float_as_int(x);
    x += __int_as_float(__builtin_amdgcn_update_dpp(0, v, 0x141, 0xF, 0xF, true)); // row_half_mirror
    v = __float_as_int(x);
    x += __int_as_float(__builtin_amdgcn_update_dpp(0, v, 0x140, 0xF, 0xF, true)); // row_mirror
    return x;
}

// ============================ CSR build ============================
__global__ __launch_bounds__(256) void k_hist(const int* __restrict__ dstv, int* __restrict__ deg) {
    int e = blockIdx.x * 256 + threadIdx.x;
    if (e < NE) atomicAdd(&deg[dstv[e]], 1);
}

// scan1 also zeroes cnt (needed by k_scatter, which runs after)
__global__ __launch_bounds__(256) void k_scan1(const int* __restrict__ deg, int* __restrict__ bsum,
                                               int* __restrict__ cnt) {
    __shared__ int ws[4];
    const int tid = threadIdx.x, lane = tid & 63, w = tid >> 6;
    const int i = blockIdx.x * 256 + tid;
    if (i < NN) cnt[i] = 0;
    int v = (i < NN) ? deg[i] : 0;
    #pragma unroll
    for (int off = 32; off; off >>= 1) v += __shfl_xor(v, off);
    if (lane == 0) ws[w] = v;
    __syncthreads();
    if (tid == 0) bsum[blockIdx.x] = ws[0] + ws[1] + ws[2] + ws[3];
}

// scan2 also zeroes stats (first consumed by k_tr layer 0, far downstream)
__global__ __launch_bounds__(256) void k_scan2(const int* __restrict__ bsum, int* __restrict__ boff, int nblk,
                                               float* __restrict__ stats) {
    __shared__ int ws[4];
    const int tid = threadIdx.x, lane = tid & 63, w = tid >> 6;
    for (int i = tid; i < 384; i += 256) stats[i] = 0.f;
    int v = (tid < nblk) ? bsum[tid] : 0;
    int incl = v;
    #pragma unroll
    for (int off = 1; off < 64; off <<= 1) {
        int t = __shfl_up(incl, off);
        if (lane >= off) incl += t;
    }
    if (lane == 63) ws[w] = incl;
    __syncthreads();
    int add = 0;
    for (int k = 0; k < w; ++k) add += ws[k];
    if (tid < nblk) boff[tid] = add + incl - v;
}

__global__ __launch_bounds__(256) void k_scan3(const int* __restrict__ deg, const int* __restrict__ boff,
                                               int* __restrict__ rowptr) {
    __shared__ int ws[4];
    const int tid = threadIdx.x, lane = tid & 63, w = tid >> 6;
    const int i = blockIdx.x * 256 + tid;
    int v = (i < NN) ? deg[i] : 0;
    int incl = v;
    #pragma unroll
    for (int off = 1; off < 64; off <<= 1) {
        int t = __shfl_up(incl, off);
        if (lane >= off) incl += t;
    }
    if (lane == 63) ws[w] = incl;
    __syncthreads();
    int add = boff[blockIdx.x];
    for (int k = 0; k < w; ++k) add += ws[k];
    if (i < NN) rowptr[i + 1] = add + incl;
    if (i == 0) rowptr[0] = 0;
}

__global__ __launch_bounds__(256) void k_scatter(const int* __restrict__ dstv, const int* __restrict__ srcv,
                                                 const float* __restrict__ eattr, const int* __restrict__ rowptr,
                                                 int* __restrict__ cnt, int* __restrict__ eid,
                                                 int* __restrict__ src_perm, float4* __restrict__ ea_perm,
                                                 int use_perm) {
    int e = blockIdx.x * 256 + threadIdx.x;
    if (e < NE) {
        int d = dstv[e];
        int pos = rowptr[d] + atomicAdd(&cnt[d], 1);
        eid[pos] = e;
        if (use_perm) {
            src_perm[pos] = srcv[e];
            ea_perm[(size_t)pos * 2] = ((const float4*)eattr)[e * 2];
            ea_perm[(size_t)pos * 2 + 1] = ((const float4*)eattr)[e * 2 + 1];
        }
    }
}

// ============================ GEMM: [N,64] @ [64,256] -> xl / xr ============================
// 128 rows x 128 cols per block; 8x8 microtile; K chunked x2 -> ~34KB LDS -> 4 blocks/CU.
// A staged TRANSPOSED per chunk (broadcast reads). blockIdx.y: bit0 = col half, bit1 = mat.
// BN of prev layer computed IN-KERNEL from raw stats (champion r6 config).
__global__ __launch_bounds__(256, 4) void k_gemm64(const float* __restrict__ A, const float* __restrict__ Wl,
                                                   const float* __restrict__ Wr, float* __restrict__ Cl,
                                                   float* __restrict__ Cr, const float* __restrict__ stats,
                                                   const float* __restrict__ bg, const float* __restrict__ bb) {
    __shared__ float At[32 * 132];  // 16,896 B
    __shared__ float Ws[32 * 128];  // 16,384 B
    __shared__ float sc_s[64], sh_s[64], shW_s[128];
    const int tid = threadIdx.x;
    const int mat = blockIdx.y >> 1, ch = blockIdx.y & 1;
    const float* W = mat ? Wr : Wl;
    float* C = mat ? Cr : Cl;
    const int r0b = blockIdx.x * 128;
    const int cg = tid & 15; // cols cg*4..+3 and 64+cg*4..+3
    const int rg = tid >> 4; // rows rg*8..+7

    if (stats) {
        if (tid < 64) {
            const float mu = stats[tid] * (1.0f / (float)NN);
            const float var = stats[64 + tid] * (1.0f / (float)NN) - mu * mu;
            const float rstd = rsqrtf(var + 1e-5f);
            const float sc = bg[tid] * rstd;
            sc_s[tid] = sc;
            sh_s[tid] = fmaf(-mu, sc, bb[tid]);
        }
        __syncthreads();
        if (tid < 128) {
            const float* wc = W + ch * 128 + tid;
            float s = 0.f;
            for (int k = 0; k < 64; ++k) s = fmaf(sh_s[k], wc[k * 256], s);
            shW_s[tid] = s;
        }
        __syncthreads();
    }

    float acc[8][8];
    if (stats) {
        #pragma unroll
        for (int rr = 0; rr < 8; ++rr)
            #pragma unroll
            for (int j = 0; j < 8; ++j)
                acc[rr][j] = (j < 4) ? shW_s[cg * 4 + j] : shW_s[64 + cg * 4 + (j - 4)];
    } else {
        #pragma unroll
        for (int rr = 0; rr < 8; ++rr)
            #pragma unroll
            for (int j = 0; j < 8; ++j) acc[rr][j] = 0.f;
    }

    for (int kc = 0; kc < 2; ++kc) {
        if (kc) __syncthreads();
        for (int i = tid; i < 1024; i += 256) {
            const int k = i >> 5, c4 = i & 31;
            float4 v = ((const float4*)W)[(kc * 32 + k) * 64 + ch * 32 + c4];
            if (stats) {
                const float s = sc_s[kc * 32 + k];
                v.x *= s; v.y *= s; v.z *= s; v.w *= s;
            }
            ((float4*)Ws)[i] = v;
        }
        for (int i = tid; i < 1024; i += 256) {
            const int r = i >> 3, c4 = i & 7;
            const int rgl = (r0b + r < NN) ? (r0b + r) : (NN - 1);
            const float4 v = ((const float4*)A)[rgl * 16 + kc * 8 + c4];
            At[(c4 * 4 + 0) * 132 + r] = v.x;
            At[(c4 * 4 + 1) * 132 + r] = v.y;
            At[(c4 * 4 + 2) * 132 + r] = v.z;
            At[(c4 * 4 + 3) * 132 + r] = v.w;
        }
        __syncthreads();
        #pragma unroll 4
        for (int k = 0; k < 32; ++k) {
            const float4 a0 = *(const float4*)(At + k * 132 + rg * 8);
            const float4 a1 = *(const float4*)(At + k * 132 + rg * 8 + 4);
            const float4 w0 = *(const float4*)(Ws + k * 128 + cg * 4);
            const float4 w1 = *(const float4*)(Ws + k * 128 + 64 + cg * 4);
            const float ar[8] = {a0.x, a0.y, a0.z, a0.w, a1.x, a1.y, a1.z, a1.w};
            #pragma unroll
            for (int rr = 0; rr < 8; ++rr) {
                acc[rr][0] = fmaf(ar[rr], w0.x, acc[rr][0]);
                acc[rr][1] = fmaf(ar[rr], w0.y, acc[rr][1]);
                acc[rr][2] = fmaf(ar[rr], w0.z, acc[rr][2]);
                acc[rr][3] = fmaf(ar[rr], w0.w, acc[rr][3]);
                acc[rr][4] = fmaf(ar[rr], w1.x, acc[rr][4]);
                acc[rr][5] = fmaf(ar[rr], w1.y, acc[rr][5]);
                acc[rr][6] = fmaf(ar[rr], w1.z, acc[rr][6]);
                acc[rr][7] = fmaf(ar[rr], w1.w, acc[rr][7]);
            }
        }
    }
    #pragma unroll
    for (int rr = 0; rr < 8; ++rr) {
        const int r = r0b + rg * 8 + rr;
        if (r < NN) {
            float* cp = C + (size_t)r * 256 + ch * 128 + cg * 4;
            *(float4*)cp = make_float4(acc[rr][0], acc[rr][1], acc[rr][2], acc[rr][3]);
            *(float4*)(cp + 64) = make_float4(acc[rr][4], acc[rr][5], acc[rr][6], acc[rr][7]);
        }
    }
}

// ============================ Fused edge kernel (champion: 3-slot, grid 2048) ============================
template <bool PERM>
__global__ __launch_bounds__(256, 4) void k_agg(const float* __restrict__ xl, float* __restrict__ xragg,
                                                const float* __restrict__ att, const float* __restrict__ gatb,
                                                const int* __restrict__ rowptr, const int* __restrict__ eid,
                                                const int* __restrict__ srcv, const float* __restrict__ eattr,
                                                const int* __restrict__ src_perm, const float4* __restrict__ ea_perm,
                                                const float* __restrict__ We) {
    const int lane = threadIdx.x & 63;
    const float4 we0 = ((const float4*)(We + 0 * 256))[lane];
    const float4 we1 = ((const float4*)(We + 1 * 256))[lane];
    const float4 we2 = ((const float4*)(We + 2 * 256))[lane];
    const float4 we3 = ((const float4*)(We + 3 * 256))[lane];
    const float4 we4 = ((const float4*)(We + 4 * 256))[lane];
    const float4 we5 = ((const float4*)(We + 5 * 256))[lane];
    const float4 we6 = ((const float4*)(We + 6 * 256))[lane];
    const float4 we7 = ((const float4*)(We + 7 * 256))[lane];
    const float4 attf = ((const float4*)att)[lane];
    const float4 gbf = ((const float4*)gatb)[lane];
    const int nw = gridDim.x * (blockDim.x >> 6);
    const int wid = blockIdx.x * (blockDim.x >> 6) + (threadIdx.x >> 6);

#define LOADE(X, idx)                                                          \
    {                                                                          \
        int s_;                                                                \
        const float4* eap_;                                                    \
        if (PERM) {                                                            \
            s_ = src_perm[idx];                                                \
            eap_ = ea_perm + (size_t)(idx) * 2;                                \
        } else {                                                               \
            const int e_ = eid[idx];                                           \
            s_ = srcv[e_];                                                     \
            eap_ = (const float4*)(eattr + (size_t)e_ * 8);                    \
        }                                                                      \
        X##x = ((const float4*)(xl + (size_t)s_ * 256))[lane];                 \
        X##a = eap_[0];                                                        \
        X##b = eap_[1];                                                        \
    }

#define PROC(X)                                                                \
    {                                                                          \
        float v0 = fmaf(X##a.x, we0.x, xr.x), v1 = fmaf(X##a.x, we0.y, xr.y);  \
        float v2 = fmaf(X##a.x, we0.z, xr.z), v3 = fmaf(X##a.x, we0.w, xr.w);  \
        v0 = fmaf(X##a.y, we1.x, v0); v1 = fmaf(X##a.y, we1.y, v1);            \
        v2 = fmaf(X##a.y, we1.z, v2); v3 = fmaf(X##a.y, we1.w, v3);            \
        v0 = fmaf(X##a.z, we2.x, v0); v1 = fmaf(X##a.z, we2.y, v1);            \
        v2 = fmaf(X##a.z, we2.z, v2); v3 = fmaf(X##a.z, we2.w, v3);            \
        v0 = fmaf(X##a.w, we3.x, v0); v1 = fmaf(X##a.w, we3.y, v1);            \
        v2 = fmaf(X##a.w, we3.z, v2); v3 = fmaf(X##a.w, we3.w, v3);            \
        v0 = fmaf(X##b.x, we4.x, v0); v1 = fmaf(X##b.x, we4.y, v1);            \
        v2 = fmaf(X##b.x, we4.z, v2); v3 = fmaf(X##b.x, we4.w, v3);            \
        v0 = fmaf(X##b.y, we5.x, v0); v1 = fmaf(X##b.y, we5.y, v1);            \
        v2 = fmaf(X##b.y, we5.z, v2); v3 = fmaf(X##b.y, we5.w, v3);            \
        v0 = fmaf(X##b.z, we6.x, v0); v1 = fmaf(X##b.z, we6.y, v1);            \
        v2 = fmaf(X##b.z, we6.z, v2); v3 = fmaf(X##b.z, we6.w, v3);            \
        v0 = fmaf(X##b.w, we7.x, v0); v1 = fmaf(X##b.w, we7.y, v1);            \
        v2 = fmaf(X##b.w, we7.z, v2); v3 = fmaf(X##b.w, we7.w, v3);            \
        v0 += X##x.x; v1 += X##x.y; v2 += X##x.z; v3 += X##x.w;                \
        v0 = fmaxf(v0, 0.2f * v0); v1 = fmaxf(v1, 0.2f * v1);                  \
        v2 = fmaxf(v2, 0.2f * v2); v3 = fmaxf(v3, 0.2f * v3);                  \
        float part = v0 * attf.x;                                              \
        part = fmaf(v1, attf.y, part);                                         \
        part = fmaf(v2, attf.z, part);                                         \
        part = fmaf(v3, attf.w, part);                                         \
        part = dpp_add16(part);                                                \
        const float p = __expf(part);                                          \
        den += p;                                                              \
        c0 = fmaf(p, X##x.x, c0);                                              \
        c1 = fmaf(p, X##x.y, c1);                                              \
        c2 = fmaf(p, X##x.z, c2);                                              \
        c3 = fmaf(p, X##x.w, c3);                                              \
    }

    for (int n = wid; n < NN; n += nw) {
        const int e0 = rowptr[n], e1 = rowptr[n + 1];
        const float4 xr = ((const float4*)(xragg + (size_t)n * 256))[lane];
        float den = 0.f, c0 = 0.f, c1 = 0.f, c2 = 0.f, c3 = 0.f;
        float4 Ax, Aa, Ab, Bx, Ba, Bb, Cx, Ca, Cb;
        const int cnt = e1 - e0;
        if (cnt > 0) {
            LOADE(A, e0);
            if (cnt > 1) LOADE(B, e0 + 1);
            if (cnt > 2) LOADE(C, e0 + 2);
            int i = e0;
            for (; i + 5 < e1; i += 3) {
                PROC(A);
                LOADE(A, i + 3);
                PROC(B);
                LOADE(B, i + 4);
                PROC(C);
                LOADE(C, i + 5);
            }
            const int m = e1 - i; // 1..5
            PROC(A);
            if (m >= 2) PROC(B);
            if (m >= 3) PROC(C);
            if (m >= 4) { LOADE(A, i + 3); PROC(A); }
            if (m == 5) { LOADE(B, i + 4); PROC(B); }
        }
        float4 o;
        if (cnt > 0) {
            const float inv = 1.0f / den;
            o.x = fmaf(c0, inv, gbf.x);
            o.y = fmaf(c1, inv, gbf.y);
            o.z = fmaf(c2, inv, gbf.z);
            o.w = fmaf(c3, inv, gbf.w);
        } else {
            o = gbf;
        }
        ((float4*)(xragg + (size_t)n * 256))[lane] = o;
    }
#undef LOADE
#undef PROC
}

// ============================ tr GEMM: [N,256]@[256,64] + bias, relu, BN stats ============================
// 256 rows x 64 cols per block, 256 threads, 8x8 microtile; K chunked x8 (~42KB LDS) -- champion config.
__global__ __launch_bounds__(256, 4) void k_tr(const float* __restrict__ A, const float* __restrict__ W,
                                               const float* __restrict__ bias, float* __restrict__ Hout,
                                               float* __restrict__ stats) {
    __shared__ float At[32 * 260]; // 33,280 B
    __shared__ float Ws[32 * 64];  // 8,192 B
    __shared__ float red[128];
    const int tid = threadIdx.x;
    const int cg = tid & 7;  // cols cg*8..+7
    const int rg = tid >> 3; // rows rg*8..+7 (0..31)
    const int r0b = blockIdx.x * 256;

    float acc[8][8];
    #pragma unroll
    for (int rr = 0; rr < 8; ++rr)
        #pragma unroll
        for (int j = 0; j < 8; ++j)
            acc[rr][j] = bias[cg * 8 + j];

    for (int kc = 0; kc < 8; ++kc) {
        if (kc) __syncthreads();
        for (int i = tid; i < 512; i += 256)
            ((float4*)Ws)[i] = ((const float4*)(W + kc * 2048))[i];
        for (int i = tid; i < 2048; i += 256) {
            const int r = i >> 3, c4 = i & 7;
            const int rgl = (r0b + r < NN) ? (r0b + r) : (NN - 1);
            const float4 v = ((const float4*)A)[(size_t)rgl * 64 + kc * 8 + c4];
            At[(c4 * 4 + 0) * 260 + r] = v.x;
            At[(c4 * 4 + 1) * 260 + r] = v.y;
            At[(c4 * 4 + 2) * 260 + r] = v.z;
            At[(c4 * 4 + 3) * 260 + r] = v.w;
        }
        __syncthreads();
        #pragma unroll 4
        for (int k = 0; k < 32; ++k) {
            const float4 a0 = *(const float4*)(At + k * 260 + rg * 8);
            const float4 a1 = *(const float4*)(At + k * 260 + rg * 8 + 4);
            const float4 w0 = *(const float4*)(Ws + k * 64 + cg * 8);
            const float4 w1 = *(const float4*)(Ws + k * 64 + cg * 8 + 4);
            const float ar[8] = {a0.x, a0.y, a0.z, a0.w, a1.x, a1.y, a1.z, a1.w};
            #pragma unroll
            for (int rr = 0; rr < 8; ++rr) {
                acc[rr][0] = fmaf(ar[rr], w0.x, acc[rr][0]);
                acc[rr][1] = fmaf(ar[rr], w0.y, acc[rr][1]);
                acc[rr][2] = fmaf(ar[rr], w0.z, acc[rr][2]);
                acc[rr][3] = fmaf(ar[rr], w0.w, acc[rr][3]);
                acc[rr][4] = fmaf(ar[rr], w1.x, acc[rr][4]);
                acc[rr][5] = fmaf(ar[rr], w1.y, acc[rr][5]);
                acc[rr][6] = fmaf(ar[rr], w1.z, acc[rr][6]);
                acc[rr][7] = fmaf(ar[rr], w1.w, acc[rr][7]);
            }
        }
    }
    float lsum[8], lsq[8];
    #pragma unroll
    for (int j = 0; j < 8; ++j) { lsum[j] = 0.f; lsq[j] = 0.f; }
    #pragma unroll
    for (int rr = 0; rr < 8; ++rr) {
        const int r = r0b + rg * 8 + rr;
        if (r < NN) {
            float v[8];
            #pragma unroll
            for (int j = 0; j < 8; ++j) {
                v[j] = fmaxf(acc[rr][j], 0.f);
                lsum[j] += v[j];
                lsq[j] = fmaf(v[j], v[j], lsq[j]);
            }
            float* hp = Hout + (size_t)r * 64;
            *(float4*)(hp + cg * 8) = make_float4(v[0], v[1], v[2], v[3]);
            *(float4*)(hp + cg * 8 + 4) = make_float4(v[4], v[5], v[6], v[7]);
        }
    }
    __syncthreads();
    if (tid < 128) red[tid] = 0.f;
    __syncthreads();
    #pragma unroll
    for (int j = 0; j < 8; ++j) {
        atomicAdd(&red[cg * 8 + j], lsum[j]);
        atomicAdd(&red[64 + cg * 8 + j], lsq[j]);
    }
    __syncthreads();
    if (tid < 64) {
        atomicAdd(&stats[tid], red[tid]);
        atomicAdd(&stats[64 + tid], red[64 + tid]);
    }
}

// ============================ fused gate + pool + BN fold + MLP head ============================
__global__ __launch_bounds__(256) void k_poolhead(const float* __restrict__ h, const float* __restrict__ gw,
                                                  const int* __restrict__ bidx, const float* __restrict__ stats,
                                                  const float* __restrict__ bg, const float* __restrict__ bb,
                                                  const float* __restrict__ fc, const float* __restrict__ nrot,
                                                  const float* __restrict__ W1, const float* __restrict__ b1,
                                                  const float* __restrict__ W2, const float* __restrict__ b2,
                                                  const float* __restrict__ W3, const float* __restrict__ b3,
                                                  const float* __restrict__ W4, const float* __restrict__ b4,
                                                  float* __restrict__ out) {
    __shared__ float gate_s[1024];
    __shared__ float red[4];
    __shared__ float pp[4][64];
    __shared__ float scb[64], shb[64];
    __shared__ float z[66], a1[256], a2[128], a3[64];
    const int b = blockIdx.x, tid = threadIdx.x, lane = tid & 63, w = tid >> 6;
    if (tid < 64) {
        const float mu = stats[tid] * (1.0f / (float)NN);
        const float var = stats[64 + tid] * (1.0f / (float)NN) - mu * mu;
        const float rstd = rsqrtf(var + 1e-5f);
        const float sc = bg[tid] * rstd;
        scb[tid] = sc;
        shb[tid] = fmaf(-mu, sc, bb[tid]);
    }
    int lo = 0, hi = NN;
    while (lo < hi) { int mid = (lo + hi) >> 1; if (bidx[mid] < b) lo = mid + 1; else hi = mid; }
    const int s0 = lo;
    lo = 0; hi = NN;
    while (lo < hi) { int mid = (lo + hi) >> 1; if (bidx[mid] < b + 1) lo = mid + 1; else hi = mid; }
    const int s1 = lo;
    const int seg = s1 - s0;
    __syncthreads();

    const float gwv = gw[lane] * scb[lane];
    for (int i = s0 + w; i < s1; i += 4) {
        float p = h[(size_t)i * 64 + lane] * gwv;
        #pragma unroll
        for (int off = 32; off; off >>= 1) p += __shfl_xor(p, off);
        if (lane == 0) gate_s[i - s0] = p;
    }
    __syncthreads();
    float v = NINF;
    for (int i = tid; i < seg; i += 256) v = fmaxf(v, gate_s[i]);
    #pragma unroll
    for (int off = 32; off; off >>= 1) v = fmaxf(v, __shfl_xor(v, off));
    if (lane == 0) red[w] = v;
    __syncthreads();
    const float mx = fmaxf(fmaxf(red[0], red[1]), fmaxf(red[2], red[3]));
    __syncthreads();
    float d = 0.f;
    for (int i = tid; i < seg; i += 256) {
        const float ex = __expf(gate_s[i] - mx);
        gate_s[i] = ex;
        d += ex;
    }
    #pragma unroll
    for (int off = 32; off; off >>= 1) d += __shfl_xor(d, off);
    if (lane == 0) red[w] = d;
    __syncthreads();
    const float den = red[0] + red[1] + red[2] + red[3];
    const int c = tid & 63, ro = tid >> 6;
    float acc = 0.f;
    for (int i = s0 + ro; i < s1; i += 4) acc = fmaf(gate_s[i - s0], h[(size_t)i * 64 + c], acc);
    pp[ro][c] = acc;
    __syncthreads();
    if (tid < 64) {
        const float raw = (pp[0][tid] + pp[1][tid] + pp[2][tid] + pp[3][tid]) / den;
        z[tid] = (seg > 0) ? fmaf(raw, scb[tid], shb[tid]) : shb[tid];
    }
    if (tid == 64) z[64] = fc[b];
    if (tid == 65) z[65] = nrot[b];
    __syncthreads();
    float s = b1[tid];
    for (int k = 0; k < 66; ++k) s = fmaf(z[k], W1[k * 256 + tid], s);
    a1[tid] = fmaxf(s, 0.f);
    __syncthreads();
    if (tid < 128) {
        float s2 = b2[tid];
        for (int k = 0; k < 256; ++k) s2 = fmaf(a1[k], W2[k * 128 + tid], s2);
        a2[tid] = fmaxf(s2, 0.f);
    }
    __syncthreads();
    if (tid < 64) {
        float s3 = b3[tid];
        for (int k = 0; k < 128; ++k) s3 = fmaf(a2[k], W3[k * 64 + tid], s3);
        a3[tid] = fmaxf(s3, 0.f);
    }
    __syncthreads();
    if (tid < 64) {
        float p = a3[tid] * W4[tid];
        #pragma unroll
        for (int off = 32; off; off >>= 1) p += __shfl_xor(p, off);
        if (tid == 0) out[b] = p + b4[0];
    }
}

// ============================ launch ============================
extern "C" void kernel_launch(void* const* d_in, const int* in_sizes, int n_in,
                              void* d_out, int out_size, void* d_ws, size_t ws_size,
                              hipStream_t stream) {
    const float* x     = (const float*)d_in[0];
    const int*   ei    = (const int*)d_in[1];
    const float* eattr = (const float*)d_in[2];
    const float* fcv   = (const float*)d_in[3];
    const float* nrot  = (const float*)d_in[4];
    const int*   bidx  = (const int*)d_in[5];
    const float* Wl    = (const float*)d_in[6];
    const float* Wr    = (const float*)d_in[7];
    const float* We    = (const float*)d_in[8];
    const float* att   = (const float*)d_in[9];
    const float* gatb  = (const float*)d_in[10];
    const float* trW   = (const float*)d_in[11];
    const float* trb   = (const float*)d_in[12];
    const float* bng   = (const float*)d_in[13];
    const float* bnb   = (const float*)d_in[14];
    const float* gateW = (const float*)d_in[15];
    const float* W1    = (const float*)d_in[17];
    const float* b1    = (const float*)d_in[18];
    const float* W2    = (const float*)d_in[19];
    const float* b2    = (const float*)d_in[20];
    const float* W3    = (const float*)d_in[21];
    const float* b3    = (const float*)d_in[22];
    const float* W4    = (const float*)d_in[23];
    const float* b4    = (const float*)d_in[24];
    float* out = (float*)d_out;

    const int* srcv = ei;
    const int* dstv = ei + NE;

    char* w = (char*)d_ws;
    float*  xl       = (float*)(w);                 // 51,200,000
    float*  xragg    = (float*)(w + 51200000);      // 51,200,000 (xr in, agg out)
    float*  hbuf     = (float*)(w + 102400000);     // 12,800,000
    int*    deg      = (int*)  (w + 102400000);     // overlaps hbuf (dead before first k_tr)
    int*    cnt      = (int*)  (w + 102600000);     // overlaps hbuf
    int*    eid      = (int*)  (w + 115200000);     // 1,600,000
    int*    rowptr   = (int*)  (w + 116800000);     // 200,004
    float*  stats    = (float*)(w + 117000064);     // 1,536 (3 * 128 * 4)
    int*    bsum     = (int*)  (w + 117004096);     // 784
    int*    boff     = (int*)  (w + 117006144);     // 784
    int*    src_perm = (int*)  (w + 117042048);     // 1,600,000
    float4* ea_perm  = (float4*)(w + 118642048);    // 12,800,000 -> 131,442,048
    const bool use_perm = (ws_size >= (size_t)131442048);
    const int NBLK = (NN + 255) / 256; // 196

    hipMemsetAsync(deg, 0, 200000, stream);
    k_hist<<<(NE + 255) / 256, 256, 0, stream>>>(dstv, deg);
    k_scan1<<<NBLK, 256, 0, stream>>>(deg, bsum, cnt);
    k_scan2<<<1, 256, 0, stream>>>(bsum, boff, NBLK, stats);
    k_scan3<<<NBLK, 256, 0, stream>>>(deg, boff, rowptr);
    k_scatter<<<(NE + 255) / 256, 256, 0, stream>>>(dstv, srcv, eattr, rowptr, cnt, eid,
                                                    src_perm, ea_perm, use_perm ? 1 : 0);

    const float* hin = x;
    for (int l = 0; l < 3; ++l) {
        const float* st = (l == 0) ? nullptr : (stats + (l - 1) * 128);
        const float* g  = (l == 0) ? nullptr : (bng + (l - 1) * 64);
        const float* bb = (l == 0) ? nullptr : (bnb + (l - 1) * 64);
        dim3 gg((NN + 127) / 128, 4);
        k_gemm64<<<gg, 256, 0, stream>>>(hin, Wl + l * 16384, Wr + l * 16384, xl, xragg, st, g, bb);
        if (use_perm)
            k_agg<true><<<2048, 256, 0, stream>>>(xl, xragg, att + l * 256, gatb + l * 256, rowptr,
                                                  eid, srcv, eattr, src_perm, ea_perm, We + l * 2048);
        else
            k_agg<false><<<2048, 256, 0, stream>>>(xl, xragg, att + l * 256, gatb + l * 256, rowptr,
                                                   eid, srcv, eattr, src_perm, ea_perm, We + l * 2048);
        k_tr<<<(NN + 255) / 256, 256, 0, stream>>>(xragg, trW + l * 16384, trb + l * 64, hbuf, stats + l * 128);
        hin = hbuf;
    }
    k_poolhead<<<NB, 256, 0, stream>>>(hbuf, gateW, bidx, stats + 2 * 128, bng + 128, bnb + 128,
                                       fcv, nrot, W1, b1, W2, b2, W3, b3, W4, b4, out);
}